// Round 11
// baseline (148.824 us; speedup 1.0000x reference)
//
#include <hip/hip_runtime.h>
#include <cstdint>
#include <cstddef>

// Problem constants
constexpr int NPTS   = 65536;
constexpr int B      = 256;
constexpr int CHUNKS = 8;              // chunks per row (stream phase)
constexpr int CHUNK  = NPTS / CHUNKS;  // 8192 elements
constexpr int CCAP   = 160;            // per-chunk cap (mean 82, sigma 9 -> +8.7 sigma)
constexpr int NBLK   = B * CHUNKS;     // 2048 stream blocks
constexpr int TPB    = 1024;           // 16 waves/block -> 4 waves/SIMD

// Workspace layout (word offsets) — only the kA -> kB handoff remains.
constexpr size_t WSO_CBUF = 0;                       // NBLK*CCAP u64 = 655360 words
constexpr size_t WSO_PSUM = (size_t)NBLK * CCAP * 2; // NBLK floats
constexpr size_t WSO_CCNT = WSO_PSUM + NBLK;         // NBLK ints
// total ~2.51 MiB

__device__ __forceinline__ float clipp(float x) {
    return fminf(fmaxf(x, 1e-5f), 0.99999f);
}
__device__ __forceinline__ int cand_bin(float v) {
    int b = (int)((v - 0.99f) * 102400.0f);   // 1024 bins over [0.99, 1.0)
    return min(max(b, 0), 1023);
}
// Single canonical fma order for ALL projection dots (bitwise-identical d).
__device__ __forceinline__ float dot8v(float4 a, float4 b, float4 n0, float4 n1) {
    float d = a.x * n0.x;
    d = fmaf(a.y, n0.y, d); d = fmaf(a.z, n0.z, d); d = fmaf(a.w, n0.w, d);
    d = fmaf(b.x, n1.x, d); d = fmaf(b.y, n1.y, d); d = fmaf(b.z, n1.z, d);
    d = fmaf(b.w, n1.w, d);
    return d;
}

// ---------------------------------------------------------------------------
// kA: streaming pass over the 64 MB prob matrix at HBM rate. (unchanged)
__global__ __launch_bounds__(256) void kA_stream(
    const float* __restrict__ prob, float* __restrict__ ws)
{
    __shared__ float wred[4];
    __shared__ int lcnt;
    const int tid   = threadIdx.x;
    const int row   = blockIdx.x >> 3;
    const int chunk = blockIdx.x & 7;
    if (tid == 0) lcnt = 0;
    __syncthreads();

    unsigned long long* cb = (unsigned long long*)ws + (size_t)blockIdx.x * CCAP;
    const float4* p4 = (const float4*)(prob + (size_t)row * NPTS + (size_t)chunk * CHUNK);

    float4 v[8];
    #pragma unroll
    for (int i = 0; i < 8; i++) v[i] = p4[i * 256 + tid];   // all loads in flight

    float lsum = 0.f;
    #pragma unroll
    for (int i = 0; i < 8; i++) {
        float c0 = clipp(v[i].x), c1 = clipp(v[i].y), c2 = clipp(v[i].z), c3 = clipp(v[i].w);
        lsum += (c0 + c1) + (c2 + c3);
        float mx = fmaxf(fmaxf(c0, c1), fmaxf(c2, c3));
        if (mx >= 0.99f) {
            int bi = chunk * CHUNK + (i * 256 + tid) * 4;
            float c4[4] = {c0, c1, c2, c3};
            #pragma unroll
            for (int j = 0; j < 4; j++) {
                if (c4[j] >= 0.99f) {
                    int p_ = atomicAdd(&lcnt, 1);
                    if (p_ < CCAP)
                        cb[p_] = (((unsigned long long)__float_as_uint(c4[j])) << 32)
                               | (unsigned)~(bi + j);
                }
            }
        }
    }
    #pragma unroll
    for (int off = 32; off; off >>= 1) lsum += __shfl_down(lsum, off);
    if ((tid & 63) == 0) wred[tid >> 6] = lsum;
    __syncthreads();
    if (tid == 0) {
        ws[WSO_PSUM + blockIdx.x] = (wred[0] + wred[1]) + (wred[2] + wred[3]);
        ((int*)ws)[WSO_CCNT + blockIdx.x] = min(lcnt, CCAP);
    }
}

// ---------------------------------------------------------------------------
// kB: block = row, start to finish, TPB=1024. vs R10: pass A's hot loop is
// now SIDE-EFFECT-FREE (no LDS atomics, no branches, no shuffles) — the R10
// version's in-loop atomic push + switch-batching defeated the compiler's
// pipelining (VGPR=48 proves the 16 float4s were never kept in flight).
// Candidates go into a per-thread 64-bit mask (64 iters = 1 bit each);
// pass B walks the ~5 set bits per thread privately. No clist, no atomics,
// no overflow path. Superset proof: running max <= final max, so
// d >= final-0.05 implies d >= running-0.05 -> bit set.
constexpr int CSLOTS = CHUNKS * CCAP;      // 1280
__global__ __launch_bounds__(TPB) void kB_fused(
    const float* __restrict__ points, const float* __restrict__ prob,
    float* __restrict__ ws, float* __restrict__ out)
{
    __shared__ unsigned long long cand[CSLOTS];   // 10 KB
    __shared__ unsigned long long comp[256];
    __shared__ int   hist[1024];
    __shared__ int   counts_s[CHUNKS];
    __shared__ int   ccnt_s, bt_s;
    __shared__ float sw[128];
    __shared__ float pc[128][9];                  // col 8 == 1.0f; rows 0..63 = top-64 coords
    __shared__ float sred[44][4];
    __shared__ float slotm[44];
    __shared__ float wpart[2];
    __shared__ float covm[64];
    __shared__ float t64v[64];
    __shared__ __align__(16) float nrm_s[8];
    __shared__ float plane_s, facet_s, anorm_s, sump_s;
    __shared__ float redp[16], redn[16];
    __shared__ float racc[16][4];

    const int row = blockIdx.x;
    const int tid = threadIdx.x;

    if (tid < CHUNKS) counts_s[tid] = ((const int*)ws)[WSO_CCNT + row * CHUNKS + tid];
    if (tid == 0) { ccnt_s = 0; bt_s = 0; }
    hist[tid] = 0;
    __syncthreads();

    // ---- select: gather + histogram (2 strided iterations over 1280 slots) ----
    const unsigned long long* cb = (const unsigned long long*)ws;
    #pragma unroll
    for (int r = 0; r < 2; r++) {
        int s = r * TPB + tid;
        if (s < CSLOTS) {
            int c = s / CCAP, t = s - c * CCAP;
            unsigned long long k = 0ull;
            if (t < counts_s[c]) {
                k = cb[(size_t)(row * CHUNKS + c) * CCAP + t];
                atomicAdd(&hist[cand_bin(__uint_as_float((unsigned)(k >> 32)))], 1);
            }
            cand[s] = k;
        }
    }
    __syncthreads();

    // threshold bin via one wave: suffix-scan 64 groups of 16 bins
    if (tid < 64) {
        int h[16]; int g = 0;
        #pragma unroll
        for (int k = 0; k < 16; k++) { h[k] = hist[tid * 16 + k]; g += h[k]; }
        int s = g;
        #pragma unroll
        for (int off = 1; off < 64; off <<= 1) {
            int o = __shfl_down(s, off);
            if (tid + off < 64) s += o;
        }
        int Snext = __shfl_down(s, 1);
        if (tid == 63) Snext = 0;
        if (s >= 128 && Snext < 128) {
            int acc = Snext, bt = tid * 16;
            #pragma unroll
            for (int k = 15; k >= 0; k--) {
                acc += h[k];
                if (acc >= 128) { bt = tid * 16 + k; break; }
            }
            bt_s = bt;
        }
    }
    __syncthreads();

    const int bt = bt_s;
    #pragma unroll
    for (int r = 0; r < 2; r++) {
        int s = r * TPB + tid;
        if (s < CSLOTS) {
            unsigned long long k = cand[s];
            if (k && cand_bin(__uint_as_float((unsigned)(k >> 32))) >= bt) {
                int p_ = atomicAdd(&ccnt_s, 1);
                if (p_ < 256) comp[p_] = k;
            }
        }
    }
    __syncthreads();
    const int m = min(ccnt_s, 256);

    if (tid < 128) {
        sw[tid] = 0.f;
        #pragma unroll
        for (int j = 0; j < 9; j++) pc[tid][j] = (j == 8) ? 1.f : 0.f;
    }
    if (tid < 64) t64v[tid] = 0.f;
    unsigned long long ki = 0ull;
    int rank = 0;
    if (tid < 256) {
        ki = (tid < m) ? comp[tid] : 0ull;
        for (int j = 0; j < m; j++) rank += (comp[j] > ki) ? 1 : 0;
    }
    __syncthreads();

    // scatter by rank: slots 0..127 = exact top-128 (rank order = lax.top_k)
    if (tid < m && rank < 128) {
        float v = __uint_as_float((unsigned)(ki >> 32));
        unsigned idx = ~(unsigned)(ki & 0xFFFFFFFFu);
        sw[rank] = v;
        const float4* pt = (const float4*)(points + (size_t)idx * 8);
        float4 q0 = pt[0], q1 = pt[1];
        pc[rank][0] = q0.x; pc[rank][1] = q0.y; pc[rank][2] = q0.z; pc[rank][3] = q0.w;
        pc[rank][4] = q1.x; pc[rank][5] = q1.y; pc[rank][6] = q1.z; pc[rank][7] = q1.w;
        if (rank < 64) t64v[rank] = v;
    }
    __syncthreads();

    if (tid < 128) {
        float ww = sw[tid];
        #pragma unroll
        for (int off = 32; off; off >>= 1) ww += __shfl_down(ww, off);
        if ((tid & 63) == 0) wpart[tid >> 6] = ww;
    }
    if (tid < 176) {   // moments: 44 slots x 4 partials
        int s = tid >> 2, part = tid & 3;
        int i_, j_;
        if (s < 36) {
            int rem = s; i_ = 0;
            while (rem >= 8 - i_) { rem -= 8 - i_; i_++; }
            j_ = i_ + rem;
        } else { i_ = s - 36; j_ = 8; }
        float acc = 0.f;
        for (int k = part * 32; k < part * 32 + 32; k++)
            acc += sw[k] * pc[k][i_] * pc[k][j_];
        sred[s][part] = acc;
    }
    __syncthreads();
    if (tid < 44) slotm[tid] = (sred[tid][0] + sred[tid][1]) + (sred[tid][2] + sred[tid][3]);
    __syncthreads();

    if (tid < 64) {
        float w128 = fmaxf(wpart[0] + wpart[1], 1e-6f);
        int i_ = tid >> 3, j_ = tid & 7;
        int a_ = min(i_, j_), b_ = max(i_, j_);
        int s3 = 8 * a_ - (a_ * (a_ - 1)) / 2 + (b_ - a_);
        covm[tid] = slotm[s3] / w128 - (slotm[36 + i_] / w128) * (slotm[36 + j_] / w128);
    }
    if (tid == 64) {
        anorm_s = fmaxf(wpart[0], 1e-6f);
        float s = 0.f;
        for (int c = 0; c < CHUNKS; c++) s += ws[WSO_PSUM + row * CHUNKS + c];
        sump_s = s;
    }
    __syncthreads();

    // ---- element-parallel tournament Jacobi (wave 0; others idle ~1us) ----
    if (tid < 64) {
        const int i = tid >> 3, j = tid & 7;
        float a = covm[tid];
        float v = (i == j) ? 1.f : 0.f;
        const unsigned PR[7] = {023456701u, 001234567u, 050712346u, 034067125u,
                                012305674u, 067120453u, 045671032u};
        #pragma unroll 1
        for (int sweep = 0; sweep < 6; sweep++) {
            #pragma unroll
            for (int r = 0; r < 7; r++) {
                const unsigned pk = PR[r];
                const int rp = (pk >> (3 * i)) & 7;
                const int cp = (pk >> (3 * j)) & 7;
                const int pr = min(i, rp), qr = max(i, rp);
                float app = __shfl(a, pr * 9);
                float aqq = __shfl(a, qr * 9);
                float apq = __shfl(a, pr * 8 + qr);
                float tau = 0.5f * (aqq - app);
                float den = fabsf(tau) + sqrtf(fmaf(tau, tau, apq * apq));
                float t = __fdividef(apq, den + 1e-38f);
                t = (tau < 0.f) ? -t : t;
                float cr = rsqrtf(fmaf(t, t, 1.f));
                float sr = t * cr;
                float cc = __shfl(cr, j * 9);
                float sc = __shfl(sr, j * 9);
                float oth = __shfl(a, rp * 8 + j);
                a = fmaf((i < rp) ? -sr : sr, oth, cr * a);
                float oth2 = __shfl(a, i * 8 + cp);
                a = fmaf((j < cp) ? -sc : sc, oth2, cc * a);
                float ov = __shfl(v, i * 8 + cp);
                v = fmaf((j < cp) ? -sc : sc, ov, cc * v);
            }
        }
        float dd[8];
        #pragma unroll
        for (int k = 0; k < 8; k++) dd[k] = __shfl(a, k * 9);
        float e0 = dd[0]; int i0 = 0;
        #pragma unroll
        for (int k = 1; k < 8; k++) if (dd[k] < e0) { e0 = dd[k]; i0 = k; }
        float e1 = 3.4e38f;
        #pragma unroll
        for (int k = 0; k < 8; k++) if (k != i0 && dd[k] < e1) e1 = dd[k];
        if (tid == 0) { plane_s = e0; facet_s = e0 / (e1 + 1e-6f); }
        if (j == i0) nrm_s[i] = v;     // V[:,i0]; sign-invariant downstream
    }
    __syncthreads();   // normal + scalars ready for the whole block

    // ---- pass A: global max + per-thread candidate bitmask (64 iters) ----
    // Pure load+fma+max+bit stream: no atomics/LDS/branches in the loop so
    // the compiler can software-pipeline the loads against ~225cy L2 latency.
    const float4 n0 = *(const float4*)&nrm_s[0];
    const float4 n1 = *(const float4*)&nrm_s[4];
    const float4* pq = (const float4*)points;
    float mp = -3.4e38f, mn = -3.4e38f;
    unsigned long long bm = 0ull;
    #pragma unroll 8
    for (int it = 0; it < NPTS / TPB; it++) {
        int idx = it * TPB + tid;
        float4 a = pq[(size_t)idx * 2], b = pq[(size_t)idx * 2 + 1];
        float d = dot8v(a, b, n0, n1);
        mp = fmaxf(mp, d);
        mn = fmaxf(mn, -d);
        bool c = (d >= mp - 0.05f) | (-d >= mn - 0.05f);   // running-max superset
        bm |= ((unsigned long long)(c ? 1 : 0)) << it;
    }
    #pragma unroll
    for (int off = 32; off; off >>= 1) {
        mp = fmaxf(mp, __shfl_xor(mp, off));
        mn = fmaxf(mn, __shfl_xor(mn, off));
    }
    if ((tid & 63) == 0) { redp[tid >> 6] = mp; redn[tid >> 6] = mn; }
    __syncthreads();
    float pmaxp = redp[0], pmaxn = redn[0];
    #pragma unroll
    for (int k = 1; k < 16; k++) {
        pmaxp = fmaxf(pmaxp, redp[k]);
        pmaxn = fmaxf(pmaxn, redn[k]);
    }

    // ---- pass B: exact inactive term from private bitmask (~5 bits/thread) ----
    const float* probrow = prob + (size_t)row * NPTS;
    float accp = 0.f, accn = 0.f;
    while (bm) {
        int i = __builtin_ctzll(bm);
        bm &= bm - 1;
        int idx = i * TPB + tid;
        float4 a = pq[(size_t)idx * 2], b = pq[(size_t)idx * 2 + 1];
        float d = dot8v(a, b, n0, n1);          // bitwise-identical to pass A
        float tp = 0.05f + (d - pmaxp);         // exact filter vs FINAL max
        float tn = 0.05f + (-d - pmaxn);
        if (tp > 0.f || tn > 0.f) {             // ~72 true hits per row
            float w2 = 1.0f - clipp(probrow[idx]);
            if (tp > 0.f) accp = fmaf(w2 * tp, tp, accp);
            if (tn > 0.f) accn = fmaf(w2 * tn, tn, accn);
        }
    }
    float ap = 0.f, an = 0.f;
    if (tid < 64) {   // top-64 active term; coords already in pc[rank<64]
        float w = t64v[tid];
        float4 q0 = make_float4(pc[tid][0], pc[tid][1], pc[tid][2], pc[tid][3]);
        float4 q1 = make_float4(pc[tid][4], pc[tid][5], pc[tid][6], pc[tid][7]);
        float d = dot8v(q0, q1, n0, n1);
        float sp = d - pmaxp, sn = -d - pmaxn;
        ap = w * sp * sp;                // w==0 for empty slots -> 0 contribution
        an = w * sn * sn;
    }
    #pragma unroll
    for (int off = 32; off; off >>= 1) {
        accp += __shfl_down(accp, off);
        accn += __shfl_down(accn, off);
        ap   += __shfl_down(ap, off);
        an   += __shfl_down(an, off);
    }
    if ((tid & 63) == 0) {
        int wv = tid >> 6;
        racc[wv][0] = accp; racc[wv][1] = accn; racc[wv][2] = ap; racc[wv][3] = an;
    }
    __syncthreads();

    if (tid == 0) {
        float ip = 0.f, in_ = 0.f, apf = 0.f, anf = 0.f;
        #pragma unroll
        for (int k = 0; k < 16; k++) {
            ip  += racc[k][0]; in_ += racc[k][1];
            apf += racc[k][2]; anf += racc[k][3];
        }
        float inorm = fmaxf((float)NPTS - sump_s, 1e-6f);
        float bp = (apf / anorm_s) + 0.35f * (ip / inorm);
        float bn = (anf / anorm_s) + 0.35f * (in_ / inorm);
        float bd = (bp <= bn) ? bp : bn;
        float def = fmaxf(26.0f - sump_s, 0.f);
        out[row] = plane_s + 8.0f * facet_s + 4.0f * bd + 25.0f * def * def;
    }
}

// ---------------------------------------------------------------------------
extern "C" void kernel_launch(void* const* d_in, const int* in_sizes, int n_in,
                              void* d_out, int out_size, void* d_ws, size_t ws_size,
                              hipStream_t stream) {
    const float* prob   = (const float*)d_in[0];  // (256, 65536) f32
    const float* points = (const float*)d_in[1];  // (65536, 8) f32
    float* out = (float*)d_out;                   // (256,) f32
    float* ws  = (float*)d_ws;                    // ~2.51 MiB used

    kA_stream<<<NBLK, 256, 0, stream>>>(prob, ws);
    kB_fused<<<B, TPB, 0, stream>>>(points, prob, ws, out);
}

// Round 12
// 148.771 us; speedup vs baseline: 1.0004x; 1.0004x over previous
//
#include <hip/hip_runtime.h>
#include <cstdint>
#include <cstddef>

// Problem constants
constexpr int NPTS   = 65536;
constexpr int B      = 256;
constexpr int CHUNKS = 8;              // chunks per row (stream phase)
constexpr int CHUNK  = NPTS / CHUNKS;  // 8192 elements
constexpr int CCAP   = 160;            // per-chunk cap (mean 82, sigma 9 -> +8.7 sigma)
constexpr int NBLK   = B * CHUNKS;     // 2048 stream blocks
constexpr int TPB    = 1024;           // 16 waves/block -> 4 waves/SIMD

// Workspace layout (word offsets) — only the kA -> kB handoff remains.
constexpr size_t WSO_CBUF = 0;                       // NBLK*CCAP u64 = 655360 words
constexpr size_t WSO_PSUM = (size_t)NBLK * CCAP * 2; // NBLK floats
constexpr size_t WSO_CCNT = WSO_PSUM + NBLK;         // NBLK ints
// total ~2.51 MiB

__device__ __forceinline__ float clipp(float x) {
    return fminf(fmaxf(x, 1e-5f), 0.99999f);
}
__device__ __forceinline__ int cand_bin(float v) {
    int b = (int)((v - 0.99f) * 102400.0f);   // 1024 bins over [0.99, 1.0)
    return min(max(b, 0), 1023);
}
// Single canonical fma order for ALL projection dots (bitwise-identical d).
__device__ __forceinline__ float dot8v(float4 a, float4 b, float4 n0, float4 n1) {
    float d = a.x * n0.x;
    d = fmaf(a.y, n0.y, d); d = fmaf(a.z, n0.z, d); d = fmaf(a.w, n0.w, d);
    d = fmaf(b.x, n1.x, d); d = fmaf(b.y, n1.y, d); d = fmaf(b.z, n1.z, d);
    d = fmaf(b.w, n1.w, d);
    return d;
}

// ---------------------------------------------------------------------------
// kA: streaming pass over the 64 MB prob matrix at HBM rate. (unchanged)
__global__ __launch_bounds__(256) void kA_stream(
    const float* __restrict__ prob, float* __restrict__ ws)
{
    __shared__ float wred[4];
    __shared__ int lcnt;
    const int tid   = threadIdx.x;
    const int row   = blockIdx.x >> 3;
    const int chunk = blockIdx.x & 7;
    if (tid == 0) lcnt = 0;
    __syncthreads();

    unsigned long long* cb = (unsigned long long*)ws + (size_t)blockIdx.x * CCAP;
    const float4* p4 = (const float4*)(prob + (size_t)row * NPTS + (size_t)chunk * CHUNK);

    float4 v[8];
    #pragma unroll
    for (int i = 0; i < 8; i++) v[i] = p4[i * 256 + tid];   // all loads in flight

    float lsum = 0.f;
    #pragma unroll
    for (int i = 0; i < 8; i++) {
        float c0 = clipp(v[i].x), c1 = clipp(v[i].y), c2 = clipp(v[i].z), c3 = clipp(v[i].w);
        lsum += (c0 + c1) + (c2 + c3);
        float mx = fmaxf(fmaxf(c0, c1), fmaxf(c2, c3));
        if (mx >= 0.99f) {
            int bi = chunk * CHUNK + (i * 256 + tid) * 4;
            float c4[4] = {c0, c1, c2, c3};
            #pragma unroll
            for (int j = 0; j < 4; j++) {
                if (c4[j] >= 0.99f) {
                    int p_ = atomicAdd(&lcnt, 1);
                    if (p_ < CCAP)
                        cb[p_] = (((unsigned long long)__float_as_uint(c4[j])) << 32)
                               | (unsigned)~(bi + j);
                }
            }
        }
    }
    #pragma unroll
    for (int off = 32; off; off >>= 1) lsum += __shfl_down(lsum, off);
    if ((tid & 63) == 0) wred[tid >> 6] = lsum;
    __syncthreads();
    if (tid == 0) {
        ws[WSO_PSUM + blockIdx.x] = (wred[0] + wred[1]) + (wred[2] + wred[3]);
        ((int*)ws)[WSO_CCNT + blockIdx.x] = min(lcnt, CCAP);
    }
}

// ---------------------------------------------------------------------------
// kB: block = row, start to finish, TPB=1024. Pass A combines R10's PROVEN
// load structure (switch-batched groups of 8 -> compiler keeps ~6-8 loads in
// flight; VGPR=48 and 33us scan measured) with R11's side-effect-free
// candidate recording (bitmask, COMPILE-TIME shift g*8+u — R11's runtime
// shift + unbatched loads dropped VGPR to 36 and regressed to 48us).
// Pass B walks the ~5 private bits/thread. No clist, no atomics, no cap.
constexpr int CSLOTS = CHUNKS * CCAP;      // 1280
__global__ __launch_bounds__(TPB) void kB_fused(
    const float* __restrict__ points, const float* __restrict__ prob,
    float* __restrict__ ws, float* __restrict__ out)
{
    __shared__ unsigned long long cand[CSLOTS];   // 10 KB
    __shared__ unsigned long long comp[256];
    __shared__ int   hist[1024];
    __shared__ int   counts_s[CHUNKS];
    __shared__ int   ccnt_s, bt_s;
    __shared__ float sw[128];
    __shared__ float pc[128][9];                  // col 8 == 1.0f; rows 0..63 = top-64 coords
    __shared__ float sred[44][4];
    __shared__ float slotm[44];
    __shared__ float wpart[2];
    __shared__ float covm[64];
    __shared__ float t64v[64];
    __shared__ __align__(16) float nrm_s[8];
    __shared__ float plane_s, facet_s, anorm_s, sump_s;
    __shared__ float redp[16], redn[16];
    __shared__ float racc[16][4];

    const int row = blockIdx.x;
    const int tid = threadIdx.x;

    if (tid < CHUNKS) counts_s[tid] = ((const int*)ws)[WSO_CCNT + row * CHUNKS + tid];
    if (tid == 0) { ccnt_s = 0; bt_s = 0; }
    hist[tid] = 0;
    __syncthreads();

    // ---- select: gather + histogram (2 strided iterations over 1280 slots) ----
    const unsigned long long* cb = (const unsigned long long*)ws;
    #pragma unroll
    for (int r = 0; r < 2; r++) {
        int s = r * TPB + tid;
        if (s < CSLOTS) {
            int c = s / CCAP, t = s - c * CCAP;
            unsigned long long k = 0ull;
            if (t < counts_s[c]) {
                k = cb[(size_t)(row * CHUNKS + c) * CCAP + t];
                atomicAdd(&hist[cand_bin(__uint_as_float((unsigned)(k >> 32)))], 1);
            }
            cand[s] = k;
        }
    }
    __syncthreads();

    // threshold bin via one wave: suffix-scan 64 groups of 16 bins
    if (tid < 64) {
        int h[16]; int g = 0;
        #pragma unroll
        for (int k = 0; k < 16; k++) { h[k] = hist[tid * 16 + k]; g += h[k]; }
        int s = g;
        #pragma unroll
        for (int off = 1; off < 64; off <<= 1) {
            int o = __shfl_down(s, off);
            if (tid + off < 64) s += o;
        }
        int Snext = __shfl_down(s, 1);
        if (tid == 63) Snext = 0;
        if (s >= 128 && Snext < 128) {
            int acc = Snext, bt = tid * 16;
            #pragma unroll
            for (int k = 15; k >= 0; k--) {
                acc += h[k];
                if (acc >= 128) { bt = tid * 16 + k; break; }
            }
            bt_s = bt;
        }
    }
    __syncthreads();

    const int bt = bt_s;
    #pragma unroll
    for (int r = 0; r < 2; r++) {
        int s = r * TPB + tid;
        if (s < CSLOTS) {
            unsigned long long k = cand[s];
            if (k && cand_bin(__uint_as_float((unsigned)(k >> 32))) >= bt) {
                int p_ = atomicAdd(&ccnt_s, 1);
                if (p_ < 256) comp[p_] = k;
            }
        }
    }
    __syncthreads();
    const int m = min(ccnt_s, 256);

    if (tid < 128) {
        sw[tid] = 0.f;
        #pragma unroll
        for (int j = 0; j < 9; j++) pc[tid][j] = (j == 8) ? 1.f : 0.f;
    }
    if (tid < 64) t64v[tid] = 0.f;
    unsigned long long ki = 0ull;
    int rank = 0;
    if (tid < 256) {
        ki = (tid < m) ? comp[tid] : 0ull;
        for (int j = 0; j < m; j++) rank += (comp[j] > ki) ? 1 : 0;
    }
    __syncthreads();

    // scatter by rank: slots 0..127 = exact top-128 (rank order = lax.top_k)
    if (tid < m && rank < 128) {
        float v = __uint_as_float((unsigned)(ki >> 32));
        unsigned idx = ~(unsigned)(ki & 0xFFFFFFFFu);
        sw[rank] = v;
        const float4* pt = (const float4*)(points + (size_t)idx * 8);
        float4 q0 = pt[0], q1 = pt[1];
        pc[rank][0] = q0.x; pc[rank][1] = q0.y; pc[rank][2] = q0.z; pc[rank][3] = q0.w;
        pc[rank][4] = q1.x; pc[rank][5] = q1.y; pc[rank][6] = q1.z; pc[rank][7] = q1.w;
        if (rank < 64) t64v[rank] = v;
    }
    __syncthreads();

    if (tid < 128) {
        float ww = sw[tid];
        #pragma unroll
        for (int off = 32; off; off >>= 1) ww += __shfl_down(ww, off);
        if ((tid & 63) == 0) wpart[tid >> 6] = ww;
    }
    if (tid < 176) {   // moments: 44 slots x 4 partials
        int s = tid >> 2, part = tid & 3;
        int i_, j_;
        if (s < 36) {
            int rem = s; i_ = 0;
            while (rem >= 8 - i_) { rem -= 8 - i_; i_++; }
            j_ = i_ + rem;
        } else { i_ = s - 36; j_ = 8; }
        float acc = 0.f;
        for (int k = part * 32; k < part * 32 + 32; k++)
            acc += sw[k] * pc[k][i_] * pc[k][j_];
        sred[s][part] = acc;
    }
    __syncthreads();
    if (tid < 44) slotm[tid] = (sred[tid][0] + sred[tid][1]) + (sred[tid][2] + sred[tid][3]);
    __syncthreads();

    if (tid < 64) {
        float w128 = fmaxf(wpart[0] + wpart[1], 1e-6f);
        int i_ = tid >> 3, j_ = tid & 7;
        int a_ = min(i_, j_), b_ = max(i_, j_);
        int s3 = 8 * a_ - (a_ * (a_ - 1)) / 2 + (b_ - a_);
        covm[tid] = slotm[s3] / w128 - (slotm[36 + i_] / w128) * (slotm[36 + j_] / w128);
    }
    if (tid == 64) {
        anorm_s = fmaxf(wpart[0], 1e-6f);
        float s = 0.f;
        for (int c = 0; c < CHUNKS; c++) s += ws[WSO_PSUM + row * CHUNKS + c];
        sump_s = s;
    }
    __syncthreads();

    // ---- element-parallel tournament Jacobi (wave 0; others idle ~1us) ----
    if (tid < 64) {
        const int i = tid >> 3, j = tid & 7;
        float a = covm[tid];
        float v = (i == j) ? 1.f : 0.f;
        const unsigned PR[7] = {023456701u, 001234567u, 050712346u, 034067125u,
                                012305674u, 067120453u, 045671032u};
        #pragma unroll 1
        for (int sweep = 0; sweep < 6; sweep++) {
            #pragma unroll
            for (int r = 0; r < 7; r++) {
                const unsigned pk = PR[r];
                const int rp = (pk >> (3 * i)) & 7;
                const int cp = (pk >> (3 * j)) & 7;
                const int pr = min(i, rp), qr = max(i, rp);
                float app = __shfl(a, pr * 9);
                float aqq = __shfl(a, qr * 9);
                float apq = __shfl(a, pr * 8 + qr);
                float tau = 0.5f * (aqq - app);
                float den = fabsf(tau) + sqrtf(fmaf(tau, tau, apq * apq));
                float t = __fdividef(apq, den + 1e-38f);
                t = (tau < 0.f) ? -t : t;
                float cr = rsqrtf(fmaf(t, t, 1.f));
                float sr = t * cr;
                float cc = __shfl(cr, j * 9);
                float sc = __shfl(sr, j * 9);
                float oth = __shfl(a, rp * 8 + j);
                a = fmaf((i < rp) ? -sr : sr, oth, cr * a);
                float oth2 = __shfl(a, i * 8 + cp);
                a = fmaf((j < cp) ? -sc : sc, oth2, cc * a);
                float ov = __shfl(v, i * 8 + cp);
                v = fmaf((j < cp) ? -sc : sc, ov, cc * v);
            }
        }
        float dd[8];
        #pragma unroll
        for (int k = 0; k < 8; k++) dd[k] = __shfl(a, k * 9);
        float e0 = dd[0]; int i0 = 0;
        #pragma unroll
        for (int k = 1; k < 8; k++) if (dd[k] < e0) { e0 = dd[k]; i0 = k; }
        float e1 = 3.4e38f;
        #pragma unroll
        for (int k = 0; k < 8; k++) if (k != i0 && dd[k] < e1) e1 = dd[k];
        if (tid == 0) { plane_s = e0; facet_s = e0 / (e1 + 1e-6f); }
        if (j == i0) nrm_s[i] = v;     // V[:,i0]; sign-invariant downstream
    }
    __syncthreads();   // normal + scalars ready for the whole block

    // ---- pass A: global max + candidate bitmask; 8-load batches ----
    // Threshold = running max, wave-refreshed per group: running <= final, so
    // d >= final-0.05 implies the bit is set (guaranteed superset).
    const float4 n0 = *(const float4*)&nrm_s[0];
    const float4 n1 = *(const float4*)&nrm_s[4];
    const float4* pq = (const float4*)points;
    float mp = -3.4e38f, mn = -3.4e38f;
    unsigned long long bm = 0ull;
    #pragma unroll 1
    for (int g = 0; g < 8; g++) {
        const float4* pg = pq + (size_t)(g * 8 * TPB + tid) * 2;
        float4 a0 = pg[0],         b0 = pg[1];
        float4 a1 = pg[TPB*2],     b1 = pg[TPB*2+1];
        float4 a2 = pg[TPB*4],     b2 = pg[TPB*4+1];
        float4 a3 = pg[TPB*6],     b3 = pg[TPB*6+1];
        float4 a4 = pg[TPB*8],     b4 = pg[TPB*8+1];
        float4 a5 = pg[TPB*10],    b5 = pg[TPB*10+1];
        float4 a6 = pg[TPB*12],    b6 = pg[TPB*12+1];
        float4 a7 = pg[TPB*14],    b7 = pg[TPB*14+1];
        #pragma unroll
        for (int u = 0; u < 8; u++) {
            float4 a, b;
            switch (u) {
                case 0: a = a0; b = b0; break;
                case 1: a = a1; b = b1; break;
                case 2: a = a2; b = b2; break;
                case 3: a = a3; b = b3; break;
                case 4: a = a4; b = b4; break;
                case 5: a = a5; b = b5; break;
                case 6: a = a6; b = b6; break;
                default: a = a7; b = b7; break;
            }
            float d = dot8v(a, b, n0, n1);
            mp = fmaxf(mp, d);
            mn = fmaxf(mn, -d);
            bool c = (d >= mp - 0.05f) | (-d >= mn - 0.05f);
            bm |= ((unsigned long long)(c ? 1 : 0)) << (g * 8 + u);   // compile-time shift
        }
        #pragma unroll
        for (int off = 32; off; off >>= 1) {   // wave refresh: tightens threshold
            mp = fmaxf(mp, __shfl_xor(mp, off));
            mn = fmaxf(mn, __shfl_xor(mn, off));
        }
    }
    if ((tid & 63) == 0) { redp[tid >> 6] = mp; redn[tid >> 6] = mn; }
    __syncthreads();
    float pmaxp = redp[0], pmaxn = redn[0];
    #pragma unroll
    for (int k = 1; k < 16; k++) {
        pmaxp = fmaxf(pmaxp, redp[k]);
        pmaxn = fmaxf(pmaxn, redn[k]);
    }

    // ---- pass B: exact inactive term from private bitmask (~5 bits/thread) ----
    const float* probrow = prob + (size_t)row * NPTS;
    float accp = 0.f, accn = 0.f;
    while (bm) {
        int i = __builtin_ctzll(bm);
        bm &= bm - 1;
        int idx = (i >> 3) * 8 * TPB + (i & 7) * TPB + tid;   // matches pass-A layout
        float4 a = pq[(size_t)idx * 2], b = pq[(size_t)idx * 2 + 1];
        float d = dot8v(a, b, n0, n1);          // bitwise-identical to pass A
        float tp = 0.05f + (d - pmaxp);         // exact filter vs FINAL max
        float tn = 0.05f + (-d - pmaxn);
        if (tp > 0.f || tn > 0.f) {             // ~72 true hits per row
            float w2 = 1.0f - clipp(probrow[idx]);
            if (tp > 0.f) accp = fmaf(w2 * tp, tp, accp);
            if (tn > 0.f) accn = fmaf(w2 * tn, tn, accn);
        }
    }
    float ap = 0.f, an = 0.f;
    if (tid < 64) {   // top-64 active term; coords already in pc[rank<64]
        float w = t64v[tid];
        float4 q0 = make_float4(pc[tid][0], pc[tid][1], pc[tid][2], pc[tid][3]);
        float4 q1 = make_float4(pc[tid][4], pc[tid][5], pc[tid][6], pc[tid][7]);
        float d = dot8v(q0, q1, n0, n1);
        float sp = d - pmaxp, sn = -d - pmaxn;
        ap = w * sp * sp;                // w==0 for empty slots -> 0 contribution
        an = w * sn * sn;
    }
    #pragma unroll
    for (int off = 32; off; off >>= 1) {
        accp += __shfl_down(accp, off);
        accn += __shfl_down(accn, off);
        ap   += __shfl_down(ap, off);
        an   += __shfl_down(an, off);
    }
    if ((tid & 63) == 0) {
        int wv = tid >> 6;
        racc[wv][0] = accp; racc[wv][1] = accn; racc[wv][2] = ap; racc[wv][3] = an;
    }
    __syncthreads();

    if (tid == 0) {
        float ip = 0.f, in_ = 0.f, apf = 0.f, anf = 0.f;
        #pragma unroll
        for (int k = 0; k < 16; k++) {
            ip  += racc[k][0]; in_ += racc[k][1];
            apf += racc[k][2]; anf += racc[k][3];
        }
        float inorm = fmaxf((float)NPTS - sump_s, 1e-6f);
        float bp = (apf / anorm_s) + 0.35f * (ip / inorm);
        float bn = (anf / anorm_s) + 0.35f * (in_ / inorm);
        float bd = (bp <= bn) ? bp : bn;
        float def = fmaxf(26.0f - sump_s, 0.f);
        out[row] = plane_s + 8.0f * facet_s + 4.0f * bd + 25.0f * def * def;
    }
}

// ---------------------------------------------------------------------------
extern "C" void kernel_launch(void* const* d_in, const int* in_sizes, int n_in,
                              void* d_out, int out_size, void* d_ws, size_t ws_size,
                              hipStream_t stream) {
    const float* prob   = (const float*)d_in[0];  // (256, 65536) f32
    const float* points = (const float*)d_in[1];  // (65536, 8) f32
    float* out = (float*)d_out;                   // (256,) f32
    float* ws  = (float*)d_ws;                    // ~2.51 MiB used

    kA_stream<<<NBLK, 256, 0, stream>>>(prob, ws);
    kB_fused<<<B, TPB, 0, stream>>>(points, prob, ws, out);
}

// Round 13
// 132.594 us; speedup vs baseline: 1.1224x; 1.1220x over previous
//
#include <hip/hip_runtime.h>
#include <cstdint>
#include <cstddef>

// Problem constants
constexpr int NPTS   = 65536;
constexpr int B      = 256;
constexpr int CHUNKS = 8;              // chunks per row (stream phase)
constexpr int CHUNK  = NPTS / CHUNKS;  // 8192 elements
constexpr int CCAP   = 160;            // per-chunk cap (mean 82, sigma 9 -> +8.7 sigma)
constexpr int NBLK   = B * CHUNKS;     // 2048 stream blocks
constexpr int TPB    = 1024;           // 16 waves/block -> 4 waves/SIMD
constexpr int CLCAP  = 9472;           // pass-A candidate list cap (mean ~6200, +40 sigma)

// Workspace layout (word offsets) — only the kA -> kB handoff remains.
constexpr size_t WSO_CBUF = 0;                       // NBLK*CCAP u64 = 655360 words
constexpr size_t WSO_PSUM = (size_t)NBLK * CCAP * 2; // NBLK floats
constexpr size_t WSO_CCNT = WSO_PSUM + NBLK;         // NBLK ints
// total ~2.51 MiB

__device__ __forceinline__ float clipp(float x) {
    return fminf(fmaxf(x, 1e-5f), 0.99999f);
}
__device__ __forceinline__ int cand_bin(float v) {
    int b = (int)((v - 0.99f) * 102400.0f);   // 1024 bins over [0.99, 1.0)
    return min(max(b, 0), 1023);
}
// Single canonical fma order for ALL projection dots (bitwise-identical d).
__device__ __forceinline__ float dot8v(float4 a, float4 b, float4 n0, float4 n1) {
    float d = a.x * n0.x;
    d = fmaf(a.y, n0.y, d); d = fmaf(a.z, n0.z, d); d = fmaf(a.w, n0.w, d);
    d = fmaf(b.x, n1.x, d); d = fmaf(b.y, n1.y, d); d = fmaf(b.z, n1.z, d);
    d = fmaf(b.w, n1.w, d);
    return d;
}

// ---------------------------------------------------------------------------
// kA: streaming pass over the 64 MB prob matrix at HBM rate. (unchanged)
__global__ __launch_bounds__(256) void kA_stream(
    const float* __restrict__ prob, float* __restrict__ ws)
{
    __shared__ float wred[4];
    __shared__ int lcnt;
    const int tid   = threadIdx.x;
    const int row   = blockIdx.x >> 3;
    const int chunk = blockIdx.x & 7;
    if (tid == 0) lcnt = 0;
    __syncthreads();

    unsigned long long* cb = (unsigned long long*)ws + (size_t)blockIdx.x * CCAP;
    const float4* p4 = (const float4*)(prob + (size_t)row * NPTS + (size_t)chunk * CHUNK);

    float4 v[8];
    #pragma unroll
    for (int i = 0; i < 8; i++) v[i] = p4[i * 256 + tid];   // all loads in flight

    float lsum = 0.f;
    #pragma unroll
    for (int i = 0; i < 8; i++) {
        float c0 = clipp(v[i].x), c1 = clipp(v[i].y), c2 = clipp(v[i].z), c3 = clipp(v[i].w);
        lsum += (c0 + c1) + (c2 + c3);
        float mx = fmaxf(fmaxf(c0, c1), fmaxf(c2, c3));
        if (mx >= 0.99f) {
            int bi = chunk * CHUNK + (i * 256 + tid) * 4;
            float c4[4] = {c0, c1, c2, c3};
            #pragma unroll
            for (int j = 0; j < 4; j++) {
                if (c4[j] >= 0.99f) {
                    int p_ = atomicAdd(&lcnt, 1);
                    if (p_ < CCAP)
                        cb[p_] = (((unsigned long long)__float_as_uint(c4[j])) << 32)
                               | (unsigned)~(bi + j);
                }
            }
        }
    }
    #pragma unroll
    for (int off = 32; off; off >>= 1) lsum += __shfl_down(lsum, off);
    if ((tid & 63) == 0) wred[tid >> 6] = lsum;
    __syncthreads();
    if (tid == 0) {
        ws[WSO_PSUM + blockIdx.x] = (wred[0] + wred[1]) + (wred[2] + wred[3]);
        ((int*)ws)[WSO_CCNT + blockIdx.x] = min(lcnt, CCAP);
    }
}

// ---------------------------------------------------------------------------
// kB: block = row, start to finish, TPB=1024. Pass A collects near-max
// candidate indices vs a wave-refreshed running-max threshold (guaranteed
// superset of d >= globalmax-0.05 since running <= global), so pass B is ~6
// list entries per thread instead of a full 2 MB rescan. Batched loads keep
// ~6-8 in flight (VGPR=48 measured); in-loop LDS atomic push measured FASTER
// than the side-effect-free bitmask variants (R10 45.7 vs R11/R12 60-62 us).
constexpr int CSLOTS = CHUNKS * CCAP;      // 1280
__global__ __launch_bounds__(TPB) void kB_fused(
    const float* __restrict__ points, const float* __restrict__ prob,
    float* __restrict__ ws, float* __restrict__ out)
{
    __shared__ unsigned long long cand[CSLOTS];   // 10 KB
    __shared__ unsigned long long comp[256];
    __shared__ int   hist[1024];
    __shared__ int   counts_s[CHUNKS];
    __shared__ int   ccnt_s, bt_s, ccand_s;
    __shared__ float sw[128];
    __shared__ float pc[128][9];                  // col 8 == 1.0f; rows 0..63 = top-64 coords
    __shared__ float sred[44][4];
    __shared__ float slotm[44];
    __shared__ float wpart[2];
    __shared__ float covm[64];
    __shared__ float t64v[64];
    __shared__ __align__(16) float nrm_s[8];
    __shared__ float plane_s, facet_s, anorm_s, sump_s;
    __shared__ float redp[16], redn[16];
    __shared__ float racc[16][4];
    __shared__ int   clist[CLCAP];                // 37 KB candidate indices

    const int row = blockIdx.x;
    const int tid = threadIdx.x;

    if (tid < CHUNKS) counts_s[tid] = ((const int*)ws)[WSO_CCNT + row * CHUNKS + tid];
    if (tid == 0) { ccnt_s = 0; bt_s = 0; ccand_s = 0; }
    hist[tid] = 0;
    __syncthreads();

    // ---- select: gather + histogram (2 strided iterations over 1280 slots) ----
    const unsigned long long* cb = (const unsigned long long*)ws;
    #pragma unroll
    for (int r = 0; r < 2; r++) {
        int s = r * TPB + tid;
        if (s < CSLOTS) {
            int c = s / CCAP, t = s - c * CCAP;
            unsigned long long k = 0ull;
            if (t < counts_s[c]) {
                k = cb[(size_t)(row * CHUNKS + c) * CCAP + t];
                atomicAdd(&hist[cand_bin(__uint_as_float((unsigned)(k >> 32)))], 1);
            }
            cand[s] = k;
        }
    }
    __syncthreads();

    // threshold bin via one wave: suffix-scan 64 groups of 16 bins
    if (tid < 64) {
        int h[16]; int g = 0;
        #pragma unroll
        for (int k = 0; k < 16; k++) { h[k] = hist[tid * 16 + k]; g += h[k]; }
        int s = g;
        #pragma unroll
        for (int off = 1; off < 64; off <<= 1) {
            int o = __shfl_down(s, off);
            if (tid + off < 64) s += o;
        }
        int Snext = __shfl_down(s, 1);
        if (tid == 63) Snext = 0;
        if (s >= 128 && Snext < 128) {
            int acc = Snext, bt = tid * 16;
            #pragma unroll
            for (int k = 15; k >= 0; k--) {
                acc += h[k];
                if (acc >= 128) { bt = tid * 16 + k; break; }
            }
            bt_s = bt;
        }
    }
    __syncthreads();

    const int bt = bt_s;
    #pragma unroll
    for (int r = 0; r < 2; r++) {
        int s = r * TPB + tid;
        if (s < CSLOTS) {
            unsigned long long k = cand[s];
            if (k && cand_bin(__uint_as_float((unsigned)(k >> 32))) >= bt) {
                int p_ = atomicAdd(&ccnt_s, 1);
                if (p_ < 256) comp[p_] = k;
            }
        }
    }
    __syncthreads();
    const int m = min(ccnt_s, 256);

    if (tid < 128) {
        sw[tid] = 0.f;
        #pragma unroll
        for (int j = 0; j < 9; j++) pc[tid][j] = (j == 8) ? 1.f : 0.f;
    }
    if (tid < 64) t64v[tid] = 0.f;
    unsigned long long ki = 0ull;
    int rank = 0;
    if (tid < 256) {
        ki = (tid < m) ? comp[tid] : 0ull;
        for (int j = 0; j < m; j++) rank += (comp[j] > ki) ? 1 : 0;
    }
    __syncthreads();

    // scatter by rank: slots 0..127 = exact top-128 (rank order = lax.top_k)
    if (tid < m && rank < 128) {
        float v = __uint_as_float((unsigned)(ki >> 32));
        unsigned idx = ~(unsigned)(ki & 0xFFFFFFFFu);
        sw[rank] = v;
        const float4* pt = (const float4*)(points + (size_t)idx * 8);
        float4 q0 = pt[0], q1 = pt[1];
        pc[rank][0] = q0.x; pc[rank][1] = q0.y; pc[rank][2] = q0.z; pc[rank][3] = q0.w;
        pc[rank][4] = q1.x; pc[rank][5] = q1.y; pc[rank][6] = q1.z; pc[rank][7] = q1.w;
        if (rank < 64) t64v[rank] = v;
    }
    __syncthreads();

    if (tid < 128) {
        float ww = sw[tid];
        #pragma unroll
        for (int off = 32; off; off >>= 1) ww += __shfl_down(ww, off);
        if ((tid & 63) == 0) wpart[tid >> 6] = ww;
    }
    if (tid < 176) {   // moments: 44 slots x 4 partials
        int s = tid >> 2, part = tid & 3;
        int i_, j_;
        if (s < 36) {
            int rem = s; i_ = 0;
            while (rem >= 8 - i_) { rem -= 8 - i_; i_++; }
            j_ = i_ + rem;
        } else { i_ = s - 36; j_ = 8; }
        float acc = 0.f;
        for (int k = part * 32; k < part * 32 + 32; k++)
            acc += sw[k] * pc[k][i_] * pc[k][j_];
        sred[s][part] = acc;
    }
    __syncthreads();
    if (tid < 44) slotm[tid] = (sred[tid][0] + sred[tid][1]) + (sred[tid][2] + sred[tid][3]);
    __syncthreads();

    if (tid < 64) {
        float w128 = fmaxf(wpart[0] + wpart[1], 1e-6f);
        int i_ = tid >> 3, j_ = tid & 7;
        int a_ = min(i_, j_), b_ = max(i_, j_);
        int s3 = 8 * a_ - (a_ * (a_ - 1)) / 2 + (b_ - a_);
        covm[tid] = slotm[s3] / w128 - (slotm[36 + i_] / w128) * (slotm[36 + j_] / w128);
    }
    if (tid == 64) {
        anorm_s = fmaxf(wpart[0], 1e-6f);
        float s = 0.f;
        for (int c = 0; c < CHUNKS; c++) s += ws[WSO_PSUM + row * CHUNKS + c];
        sump_s = s;
    }
    __syncthreads();

    // ---- element-parallel tournament Jacobi (wave 0; others idle ~1us) ----
    if (tid < 64) {
        const int i = tid >> 3, j = tid & 7;
        float a = covm[tid];
        float v = (i == j) ? 1.f : 0.f;
        const unsigned PR[7] = {023456701u, 001234567u, 050712346u, 034067125u,
                                012305674u, 067120453u, 045671032u};
        #pragma unroll 1
        for (int sweep = 0; sweep < 6; sweep++) {
            #pragma unroll
            for (int r = 0; r < 7; r++) {
                const unsigned pk = PR[r];
                const int rp = (pk >> (3 * i)) & 7;
                const int cp = (pk >> (3 * j)) & 7;
                const int pr = min(i, rp), qr = max(i, rp);
                float app = __shfl(a, pr * 9);
                float aqq = __shfl(a, qr * 9);
                float apq = __shfl(a, pr * 8 + qr);
                float tau = 0.5f * (aqq - app);
                float den = fabsf(tau) + sqrtf(fmaf(tau, tau, apq * apq));
                float t = __fdividef(apq, den + 1e-38f);
                t = (tau < 0.f) ? -t : t;
                float cr = rsqrtf(fmaf(t, t, 1.f));
                float sr = t * cr;
                float cc = __shfl(cr, j * 9);
                float sc = __shfl(sr, j * 9);
                float oth = __shfl(a, rp * 8 + j);
                a = fmaf((i < rp) ? -sr : sr, oth, cr * a);
                float oth2 = __shfl(a, i * 8 + cp);
                a = fmaf((j < cp) ? -sc : sc, oth2, cc * a);
                float ov = __shfl(v, i * 8 + cp);
                v = fmaf((j < cp) ? -sc : sc, ov, cc * v);
            }
        }
        float dd[8];
        #pragma unroll
        for (int k = 0; k < 8; k++) dd[k] = __shfl(a, k * 9);
        float e0 = dd[0]; int i0 = 0;
        #pragma unroll
        for (int k = 1; k < 8; k++) if (dd[k] < e0) { e0 = dd[k]; i0 = k; }
        float e1 = 3.4e38f;
        #pragma unroll
        for (int k = 0; k < 8; k++) if (k != i0 && dd[k] < e1) e1 = dd[k];
        if (tid == 0) { plane_s = e0; facet_s = e0 / (e1 + 1e-6f); }
        if (j == i0) nrm_s[i] = v;     // V[:,i0]; sign-invariant downstream
    }
    __syncthreads();   // normal + scalars ready for the whole block

    // ---- pass A: global max + near-max candidate collection ----
    // Loads pre-issued into named regs per 8-point group. Threshold = running
    // max, wave-refreshed each group: any d >= globalmax-0.05 also passes the
    // running test (running <= global) -> clist is a guaranteed superset.
    const float4 n0 = *(const float4*)&nrm_s[0];
    const float4 n1 = *(const float4*)&nrm_s[4];
    const float4* pq = (const float4*)points;
    float mp = -3.4e38f, mn = -3.4e38f;
    #pragma unroll 1
    for (int g = 0; g < 8; g++) {
        const float4* pg = pq + (size_t)(g * 8 * TPB + tid) * 2;
        float4 a0 = pg[0],         b0 = pg[1];
        float4 a1 = pg[TPB*2],     b1 = pg[TPB*2+1];
        float4 a2 = pg[TPB*4],     b2 = pg[TPB*4+1];
        float4 a3 = pg[TPB*6],     b3 = pg[TPB*6+1];
        float4 a4 = pg[TPB*8],     b4 = pg[TPB*8+1];
        float4 a5 = pg[TPB*10],    b5 = pg[TPB*10+1];
        float4 a6 = pg[TPB*12],    b6 = pg[TPB*12+1];
        float4 a7 = pg[TPB*14],    b7 = pg[TPB*14+1];
        #pragma unroll
        for (int u = 0; u < 8; u++) {
            float4 a, b;
            switch (u) {
                case 0: a = a0; b = b0; break;
                case 1: a = a1; b = b1; break;
                case 2: a = a2; b = b2; break;
                case 3: a = a3; b = b3; break;
                case 4: a = a4; b = b4; break;
                case 5: a = a5; b = b5; break;
                case 6: a = a6; b = b6; break;
                default: a = a7; b = b7; break;
            }
            float d = dot8v(a, b, n0, n1);
            mp = fmaxf(mp, d);
            mn = fmaxf(mn, -d);
            if (d >= mp - 0.05f || -d >= mn - 0.05f) {
                int p_ = atomicAdd(&ccand_s, 1);
                if (p_ < CLCAP) clist[p_] = (g * 8 + u) * TPB + tid;
            }
        }
        #pragma unroll
        for (int off = 32; off; off >>= 1) {   // wave refresh: tightens threshold
            mp = fmaxf(mp, __shfl_xor(mp, off));
            mn = fmaxf(mn, __shfl_xor(mn, off));
        }
    }
    if ((tid & 63) == 0) { redp[tid >> 6] = mp; redn[tid >> 6] = mn; }
    __syncthreads();
    float pmaxp = redp[0], pmaxn = redn[0];
    #pragma unroll
    for (int k = 1; k < 16; k++) {
        pmaxp = fmaxf(pmaxp, redp[k]);
        pmaxn = fmaxf(pmaxn, redn[k]);
    }

    // ---- pass B: exact inactive term from the candidate list ----
    const float* probrow = prob + (size_t)row * NPTS;
    float accp = 0.f, accn = 0.f;
    const int ccand = ccand_s;
    if (ccand <= CLCAP) {
        for (int i = tid; i < ccand; i += TPB) {
            int idx = clist[i];
            float4 a = pq[(size_t)idx * 2], b = pq[(size_t)idx * 2 + 1];
            float d = dot8v(a, b, n0, n1);      // bitwise-identical to pass A
            float tp = 0.05f + (d - pmaxp);
            float tn = 0.05f + (-d - pmaxn);
            if (tp > 0.f || tn > 0.f) {         // ~72 true hits per row
                float w2 = 1.0f - clipp(probrow[idx]);
                if (tp > 0.f) accp = fmaf(w2 * tp, tp, accp);
                if (tn > 0.f) accn = fmaf(w2 * tn, tn, accn);
            }
        }
    } else {   // astronomically-rare overflow: exact full rescan
        #pragma unroll 8
        for (int it = 0; it < NPTS / TPB; it++) {
            int idx = it * TPB + tid;
            float4 a = pq[idx * 2], b = pq[idx * 2 + 1];
            float d = dot8v(a, b, n0, n1);
            float tp = 0.05f + (d - pmaxp);
            float tn = 0.05f + (-d - pmaxn);
            if (tp > 0.f || tn > 0.f) {
                float w2 = 1.0f - clipp(probrow[idx]);
                if (tp > 0.f) accp = fmaf(w2 * tp, tp, accp);
                if (tn > 0.f) accn = fmaf(w2 * tn, tn, accn);
            }
        }
    }
    float ap = 0.f, an = 0.f;
    if (tid < 64) {   // top-64 active term; coords already in pc[rank<64]
        float w = t64v[tid];
        float4 q0 = make_float4(pc[tid][0], pc[tid][1], pc[tid][2], pc[tid][3]);
        float4 q1 = make_float4(pc[tid][4], pc[tid][5], pc[tid][6], pc[tid][7]);
        float d = dot8v(q0, q1, n0, n1);
        float sp = d - pmaxp, sn = -d - pmaxn;
        ap = w * sp * sp;                // w==0 for empty slots -> 0 contribution
        an = w * sn * sn;
    }
    #pragma unroll
    for (int off = 32; off; off >>= 1) {
        accp += __shfl_down(accp, off);
        accn += __shfl_down(accn, off);
        ap   += __shfl_down(ap, off);
        an   += __shfl_down(an, off);
    }
    if ((tid & 63) == 0) {
        int wv = tid >> 6;
        racc[wv][0] = accp; racc[wv][1] = accn; racc[wv][2] = ap; racc[wv][3] = an;
    }
    __syncthreads();

    if (tid == 0) {
        float ip = 0.f, in_ = 0.f, apf = 0.f, anf = 0.f;
        #pragma unroll
        for (int k = 0; k < 16; k++) {
            ip  += racc[k][0]; in_ += racc[k][1];
            apf += racc[k][2]; anf += racc[k][3];
        }
        float inorm = fmaxf((float)NPTS - sump_s, 1e-6f);
        float bp = (apf / anorm_s) + 0.35f * (ip / inorm);
        float bn = (anf / anorm_s) + 0.35f * (in_ / inorm);
        float bd = (bp <= bn) ? bp : bn;
        float def = fmaxf(26.0f - sump_s, 0.f);
        out[row] = plane_s + 8.0f * facet_s + 4.0f * bd + 25.0f * def * def;
    }
}

// ---------------------------------------------------------------------------
extern "C" void kernel_launch(void* const* d_in, const int* in_sizes, int n_in,
                              void* d_out, int out_size, void* d_ws, size_t ws_size,
                              hipStream_t stream) {
    const float* prob   = (const float*)d_in[0];  // (256, 65536) f32
    const float* points = (const float*)d_in[1];  // (65536, 8) f32
    float* out = (float*)d_out;                   // (256,) f32
    float* ws  = (float*)d_ws;                    // ~2.51 MiB used

    kA_stream<<<NBLK, 256, 0, stream>>>(prob, ws);
    kB_fused<<<B, TPB, 0, stream>>>(points, prob, ws, out);
}